// Round 5
// baseline (99.623 us; speedup 1.0000x reference)
//
#include <hip/hip_runtime.h>

// Radius search (L2^2), single segment, M=4096 queries x N=8192 points.
// Out (float32, concat): [0,MN) packed idx (pad -1) | [MN,MN+M+1) row splits |
//                        [MN+M+1, 2MN+M+1) packed d2 (pad 0).
//
// Exact numpy fp32 op order (NO fma):
//   q2=(qx*qx+qy*qy)+qz*qz ; p2=(px*px+py*py)+pz*pz ; qp=(qx*px+qy*py)+qz*pz
//   d2=max((q2+p2)-2*qp, 0) ; mask: d2<=r*r  (max irrelevant for mask, r2>0)
//
// 2 kernels:
//   rs_main : 256 count blocks (4 waves x 4 queries/wave, ballot masks to ws)
//             + 1536 pad-fill blocks (nontemporal float4 stores).
//   rs_write: 1024-thr blocks; every block redundantly scans counts[] in LDS
//             (replaces separate scan kernel), block 0 emits float splits,
//             16 waves/block pack idx+dist for 16 queries from masks.

typedef float f32x4 __attribute__((ext_vector_type(4)));  // native vec for nontemporal

// ---------------- main: fused count + pad-fill ----------------
__global__ void rs_main(const float* __restrict__ pts, const float* __restrict__ qs,
                        const float* __restrict__ rad,
                        int* __restrict__ counts, unsigned long long* __restrict__ masks,
                        int storeMasks,
                        float* __restrict__ out, long long MN, int N, int M,
                        int countBlocks, int fillPerRegion) {
    int bid = blockIdx.x;
    if (bid < countBlocks) {
        int t = threadIdx.x;
        int wv = t >> 6, lane = t & 63;
        int q0 = (bid * 4 + wv) * 4;  // 4 queries per wave
        if (q0 >= M) return;
        float qx[4], qy[4], qz[4], q2[4], r2[4];
#pragma unroll
        for (int j = 0; j < 4; ++j) {
            int q = q0 + j;
            bool v = (q < M);
            int qc = v ? q : (M - 1);
            float x = qs[3 * qc], y = qs[3 * qc + 1], z = qs[3 * qc + 2];
            qx[j] = x; qy[j] = y; qz[j] = z;
            q2[j] = __fadd_rn(__fadd_rn(__fmul_rn(x, x), __fmul_rn(y, y)), __fmul_rn(z, z));
            float r = rad[qc];
            r2[j] = v ? __fmul_rn(r, r) : -1.0f;  // d2>=0 never <= -1
        }
        int cnt[4] = {0, 0, 0, 0};
        int nc = N >> 6;
        unsigned long long* mq = masks + (long long)q0 * (long long)nc;
#pragma unroll 2
        for (int c = 0; c < nc; ++c) {
            int p = (c << 6) + lane;
            float px = pts[3 * p], py = pts[3 * p + 1], pz = pts[3 * p + 2];
            float p2 = __fadd_rn(__fadd_rn(__fmul_rn(px, px), __fmul_rn(py, py)),
                                 __fmul_rn(pz, pz));
            unsigned long long b[4];
#pragma unroll
            for (int j = 0; j < 4; ++j) {
                float qp = __fadd_rn(__fadd_rn(__fmul_rn(qx[j], px), __fmul_rn(qy[j], py)),
                                     __fmul_rn(qz[j], pz));
                float d2 = __fsub_rn(__fadd_rn(q2[j], p2), __fmul_rn(2.0f, qp));
                b[j] = __ballot(d2 <= r2[j]);
                cnt[j] += __popcll(b[j]);
            }
            if (storeMasks && lane == 0) {
#pragma unroll
                for (int j = 0; j < 4; ++j)
                    if (q0 + j < M) mq[(long long)j * nc + c] = b[j];
            }
        }
        if (lane == 0) {
#pragma unroll
            for (int j = 0; j < 4; ++j)
                if (q0 + j < M) counts[q0 + j] = cnt[j];
        }
    } else {
        int fb = bid - countBlocks;
        long long start;
        float val;
        int fb0;
        if (fb < fillPerRegion) { start = 0; val = -1.0f; fb0 = fb; }
        else { start = MN + (long long)M + 1; val = 0.0f; fb0 = fb - fillPerRegion; }
        long long n = MN;
        float* base = out + start;
        long long head = (long long)(((16u - ((unsigned)(size_t)base & 15u)) & 15u) >> 2);
        if (head > n) head = n;
        long long tid = (long long)fb0 * blockDim.x + threadIdx.x;
        long long nth = (long long)fillPerRegion * blockDim.x;
        for (long long i = tid; i < head; i += nth) base[i] = val;
        long long nv = (n - head) >> 2;
        f32x4* v = (f32x4*)(base + head);
        f32x4 vv = {val, val, val, val};
        for (long long i = tid; i < nv; i += nth) __builtin_nontemporal_store(vv, &v[i]);
        for (long long i = head + (nv << 2) + tid; i < n; i += nth) base[i] = val;
    }
}

// ---------------- write: in-block scan + pack ----------------
__global__ __launch_bounds__(1024) void rs_write(
    const float* __restrict__ pts, const float* __restrict__ qs,
    const float* __restrict__ rad,
    const int* __restrict__ counts, const unsigned long long* __restrict__ masks,
    int useMasks,
    float* __restrict__ out_idx, float* __restrict__ out_splits,
    float* __restrict__ out_dist, int N, int M) {
    __shared__ int s_scan[1024];
    __shared__ int s_split[4097];  // supports M <= 4096
    int t = threadIdx.x;

    // --- redundant per-block exclusive scan of counts[M] ---
    int c[4];
    int sum = 0;
    int base4 = t * 4;
#pragma unroll
    for (int i = 0; i < 4; ++i) {
        int v = (base4 + i < M) ? counts[base4 + i] : 0;
        c[i] = sum;
        sum += v;
    }
    s_scan[t] = sum;
    __syncthreads();
    for (int off = 1; off < 1024; off <<= 1) {
        int add = (t >= off) ? s_scan[t - off] : 0;
        __syncthreads();
        s_scan[t] += add;
        __syncthreads();
    }
    int excl = (t == 0) ? 0 : s_scan[t - 1];
#pragma unroll
    for (int i = 0; i < 4; ++i)
        if (base4 + i < M) s_split[base4 + i] = excl + c[i];
    if (t == 1023) s_split[M] = excl + sum;  // total
    __syncthreads();

    // --- block 0 emits float row-splits ---
    if (blockIdx.x == 0) {
        for (int i = t; i <= M; i += 1024) out_splits[i] = (float)s_split[i];
    }

    // --- 16 waves/block: pack one query each ---
    int wv = t >> 6, lane = t & 63;
    int w = blockIdx.x * 16 + wv;
    if (w >= M) return;
    float qxx = qs[3 * w], qyy = qs[3 * w + 1], qzz = qs[3 * w + 2];
    float q2 = __fadd_rn(__fadd_rn(__fmul_rn(qxx, qxx), __fmul_rn(qyy, qyy)),
                         __fmul_rn(qzz, qzz));
    long long base = s_split[w];
    int nw = N >> 6;

    if (useMasks) {
        const unsigned long long* mq = masks + (long long)w * nw;
        unsigned long long w0 = (lane < nw) ? mq[lane] : 0ull;
        unsigned long long w1 = (lane + 64 < nw) ? mq[lane + 64] : 0ull;
        int c0 = __popcll(w0), c1 = __popcll(w1);
        int i0 = c0, i1 = c1;
        for (int off = 1; off < 64; off <<= 1) {
            int t0 = __shfl_up(i0, off, 64);
            int t1 = __shfl_up(i1, off, 64);
            if (lane >= off) { i0 += t0; i1 += t1; }
        }
        int total0 = __shfl(i0, 63, 64);

        long long o = base + (i0 - c0);
        int pbase = lane << 6;
        unsigned long long mm = w0;
        while (mm) {
            int b = __ffsll((long long)mm) - 1;
            int p = pbase + b;
            float px = pts[3 * p], py = pts[3 * p + 1], pz = pts[3 * p + 2];
            float p2 = __fadd_rn(__fadd_rn(__fmul_rn(px, px), __fmul_rn(py, py)),
                                 __fmul_rn(pz, pz));
            float qp = __fadd_rn(__fadd_rn(__fmul_rn(qxx, px), __fmul_rn(qyy, py)),
                                 __fmul_rn(qzz, pz));
            float d2 = fmaxf(__fsub_rn(__fadd_rn(q2, p2), __fmul_rn(2.0f, qp)), 0.0f);
            out_idx[o] = (float)p;
            out_dist[o] = d2;
            ++o;
            mm &= mm - 1;
        }
        o = base + total0 + (i1 - c1);
        pbase = (lane + 64) << 6;
        mm = w1;
        while (mm) {
            int b = __ffsll((long long)mm) - 1;
            int p = pbase + b;
            float px = pts[3 * p], py = pts[3 * p + 1], pz = pts[3 * p + 2];
            float p2 = __fadd_rn(__fadd_rn(__fmul_rn(px, px), __fmul_rn(py, py)),
                                 __fmul_rn(pz, pz));
            float qp = __fadd_rn(__fadd_rn(__fmul_rn(qxx, px), __fmul_rn(qyy, py)),
                                 __fmul_rn(qzz, pz));
            float d2 = fmaxf(__fsub_rn(__fadd_rn(q2, p2), __fmul_rn(2.0f, qp)), 0.0f);
            out_idx[o] = (float)p;
            out_dist[o] = d2;
            ++o;
            mm &= mm - 1;
        }
    } else {
        // fallback: recompute + ballot pack (only if masks don't fit in ws)
        float r = rad[w];
        float r2 = __fmul_rn(r, r);
        int cum = 0;
        unsigned long long lanemask = (1ull << lane) - 1ull;
        for (int p0 = 0; p0 < N; p0 += 64) {
            int p = p0 + lane;
            float px = pts[3 * p], py = pts[3 * p + 1], pz = pts[3 * p + 2];
            float p2 = __fadd_rn(__fadd_rn(__fmul_rn(px, px), __fmul_rn(py, py)),
                                 __fmul_rn(pz, pz));
            float qp = __fadd_rn(__fadd_rn(__fmul_rn(qxx, px), __fmul_rn(qyy, py)),
                                 __fmul_rn(qzz, pz));
            float d2 = __fsub_rn(__fadd_rn(q2, p2), __fmul_rn(2.0f, qp));
            bool pred = (d2 <= r2);
            unsigned long long mask = __ballot(pred);
            if (pred) {
                long long pos = base + cum + __popcll(mask & lanemask);
                out_idx[pos] = (float)p;
                out_dist[pos] = fmaxf(d2, 0.0f);
            }
            cum += __popcll(mask);
        }
    }
}

extern "C" void kernel_launch(void* const* d_in, const int* in_sizes, int n_in,
                              void* d_out, int out_size, void* d_ws, size_t ws_size,
                              hipStream_t stream) {
    const float* points = (const float*)d_in[0];
    const float* queries = (const float*)d_in[1];
    const float* radii = (const float*)d_in[2];
    int N = in_sizes[0] / 3;
    int M = in_sizes[1] / 3;
    long long MN = (long long)M * (long long)N;

    float* out = (float*)d_out;
    float* out_idx = out;
    float* out_splits = out + MN;
    float* out_dist = out + MN + M + 1;

    // running-offset ws allocator (R2 lesson: never hand-sum offsets)
    char* ws = (char*)d_ws;
    size_t off = 0;
    auto take = [&](size_t bytes) -> size_t {
        size_t o = off;
        off += (bytes + 255) & ~(size_t)255;
        return o;
    };
    size_t o_counts = take((size_t)M * 4);
    size_t o_masks = take((size_t)M * (size_t)(N / 64) * 8);
    bool useMasks = (off <= ws_size) && (N <= 8192);  // write path assumes nw<=128

    int* counts = (int*)(ws + o_counts);
    unsigned long long* masks = (unsigned long long*)(ws + o_masks);

    int countBlocks = (M + 15) / 16;  // 4 waves x 4 queries per block
    int fillPerRegion = 768;
    int grid = countBlocks + 2 * fillPerRegion;
    rs_main<<<grid, 256, 0, stream>>>(points, queries, radii, counts, masks,
                                      useMasks ? 1 : 0, out, MN, N, M, countBlocks,
                                      fillPerRegion);
    int writeBlocks = (M + 15) / 16;  // 16 queries (waves) per 1024-thr block
    rs_write<<<writeBlocks, 1024, 0, stream>>>(points, queries, radii, counts, masks,
                                               useMasks ? 1 : 0, out_idx, out_splits,
                                               out_dist, N, M);
}

// Round 6
// 92.316 us; speedup vs baseline: 1.0792x; 1.0792x over previous
//
#include <hip/hip_runtime.h>

// Radius search (L2^2), single segment, M=4096 queries x N=8192 points.
// Out (float32, concat): [0,MN) packed idx (pad -1) | [MN,MN+M+1) row splits |
//                        [MN+M+1, 2MN+M+1) packed d2 (pad 0).
//
// Exact numpy fp32 op order (NO fma):
//   q2=(qx*qx+qy*qy)+qz*qz ; p2=(px*px+py*py)+pz*pz ; qp=(qx*px+qy*py)+qz*pz
//   d2=max((q2+p2)-2*qp, 0) ; mask: d2<=r*r  (max irrelevant for mask, r2>0)
//
// 2 kernels:
//   rs_main : 256 count blocks (4 waves x 4 queries/wave, ballot masks to ws)
//             + 1536 pad-fill blocks (regular float4 stores — R5's nontemporal
//             stores cost +14.5us total: nt bypasses L2 write-combining).
//   rs_write: 1024-thr blocks; every block redundantly scans counts[] in LDS
//             (replaces separate scan kernel), block 0 emits float splits,
//             16 waves/block pack idx+dist for 16 queries from masks.

typedef float f32x4 __attribute__((ext_vector_type(4)));

// ---------------- main: fused count + pad-fill ----------------
__global__ void rs_main(const float* __restrict__ pts, const float* __restrict__ qs,
                        const float* __restrict__ rad,
                        int* __restrict__ counts, unsigned long long* __restrict__ masks,
                        int storeMasks,
                        float* __restrict__ out, long long MN, int N, int M,
                        int countBlocks, int fillPerRegion) {
    int bid = blockIdx.x;
    if (bid < countBlocks) {
        int t = threadIdx.x;
        int wv = t >> 6, lane = t & 63;
        int q0 = (bid * 4 + wv) * 4;  // 4 queries per wave
        if (q0 >= M) return;
        float qx[4], qy[4], qz[4], q2[4], r2[4];
#pragma unroll
        for (int j = 0; j < 4; ++j) {
            int q = q0 + j;
            bool v = (q < M);
            int qc = v ? q : (M - 1);
            float x = qs[3 * qc], y = qs[3 * qc + 1], z = qs[3 * qc + 2];
            qx[j] = x; qy[j] = y; qz[j] = z;
            q2[j] = __fadd_rn(__fadd_rn(__fmul_rn(x, x), __fmul_rn(y, y)), __fmul_rn(z, z));
            float r = rad[qc];
            r2[j] = v ? __fmul_rn(r, r) : -1.0f;  // d2>=0 never <= -1
        }
        int cnt[4] = {0, 0, 0, 0};
        int nc = N >> 6;
        unsigned long long* mq = masks + (long long)q0 * (long long)nc;
#pragma unroll 2
        for (int c = 0; c < nc; ++c) {
            int p = (c << 6) + lane;
            float px = pts[3 * p], py = pts[3 * p + 1], pz = pts[3 * p + 2];
            float p2 = __fadd_rn(__fadd_rn(__fmul_rn(px, px), __fmul_rn(py, py)),
                                 __fmul_rn(pz, pz));
            unsigned long long b[4];
#pragma unroll
            for (int j = 0; j < 4; ++j) {
                float qp = __fadd_rn(__fadd_rn(__fmul_rn(qx[j], px), __fmul_rn(qy[j], py)),
                                     __fmul_rn(qz[j], pz));
                float d2 = __fsub_rn(__fadd_rn(q2[j], p2), __fmul_rn(2.0f, qp));
                b[j] = __ballot(d2 <= r2[j]);
                cnt[j] += __popcll(b[j]);
            }
            if (storeMasks && lane == 0) {
#pragma unroll
                for (int j = 0; j < 4; ++j)
                    if (q0 + j < M) mq[(long long)j * nc + c] = b[j];
            }
        }
        if (lane == 0) {
#pragma unroll
            for (int j = 0; j < 4; ++j)
                if (q0 + j < M) counts[q0 + j] = cnt[j];
        }
    } else {
        int fb = bid - countBlocks;
        long long start;
        float val;
        int fb0;
        if (fb < fillPerRegion) { start = 0; val = -1.0f; fb0 = fb; }
        else { start = MN + (long long)M + 1; val = 0.0f; fb0 = fb - fillPerRegion; }
        long long n = MN;
        float* base = out + start;
        long long head = (long long)(((16u - ((unsigned)(size_t)base & 15u)) & 15u) >> 2);
        if (head > n) head = n;
        long long tid = (long long)fb0 * blockDim.x + threadIdx.x;
        long long nth = (long long)fillPerRegion * blockDim.x;
        for (long long i = tid; i < head; i += nth) base[i] = val;
        long long nv = (n - head) >> 2;
        f32x4* v = (f32x4*)(base + head);
        f32x4 vv = {val, val, val, val};
        for (long long i = tid; i < nv; i += nth) v[i] = vv;  // regular stores (NOT nt)
        for (long long i = head + (nv << 2) + tid; i < n; i += nth) base[i] = val;
    }
}

// ---------------- write: in-block scan + pack ----------------
__global__ __launch_bounds__(1024) void rs_write(
    const float* __restrict__ pts, const float* __restrict__ qs,
    const float* __restrict__ rad,
    const int* __restrict__ counts, const unsigned long long* __restrict__ masks,
    int useMasks,
    float* __restrict__ out_idx, float* __restrict__ out_splits,
    float* __restrict__ out_dist, int N, int M) {
    __shared__ int s_scan[1024];
    __shared__ int s_split[4097];  // supports M <= 4096
    int t = threadIdx.x;

    // --- redundant per-block exclusive scan of counts[M] ---
    int c[4];
    int sum = 0;
    int base4 = t * 4;
#pragma unroll
    for (int i = 0; i < 4; ++i) {
        int v = (base4 + i < M) ? counts[base4 + i] : 0;
        c[i] = sum;
        sum += v;
    }
    s_scan[t] = sum;
    __syncthreads();
    for (int off = 1; off < 1024; off <<= 1) {
        int add = (t >= off) ? s_scan[t - off] : 0;
        __syncthreads();
        s_scan[t] += add;
        __syncthreads();
    }
    int excl = (t == 0) ? 0 : s_scan[t - 1];
#pragma unroll
    for (int i = 0; i < 4; ++i)
        if (base4 + i < M) s_split[base4 + i] = excl + c[i];
    if (t == 1023) s_split[M] = excl + sum;  // total
    __syncthreads();

    // --- block 0 emits float row-splits ---
    if (blockIdx.x == 0) {
        for (int i = t; i <= M; i += 1024) out_splits[i] = (float)s_split[i];
    }

    // --- 16 waves/block: pack one query each ---
    int wv = t >> 6, lane = t & 63;
    int w = blockIdx.x * 16 + wv;
    if (w >= M) return;
    float qxx = qs[3 * w], qyy = qs[3 * w + 1], qzz = qs[3 * w + 2];
    float q2 = __fadd_rn(__fadd_rn(__fmul_rn(qxx, qxx), __fmul_rn(qyy, qyy)),
                         __fmul_rn(qzz, qzz));
    long long base = s_split[w];
    int nw = N >> 6;

    if (useMasks) {
        const unsigned long long* mq = masks + (long long)w * nw;
        unsigned long long w0 = (lane < nw) ? mq[lane] : 0ull;
        unsigned long long w1 = (lane + 64 < nw) ? mq[lane + 64] : 0ull;
        int c0 = __popcll(w0), c1 = __popcll(w1);
        int i0 = c0, i1 = c1;
        for (int off = 1; off < 64; off <<= 1) {
            int t0 = __shfl_up(i0, off, 64);
            int t1 = __shfl_up(i1, off, 64);
            if (lane >= off) { i0 += t0; i1 += t1; }
        }
        int total0 = __shfl(i0, 63, 64);

        long long o = base + (i0 - c0);
        int pbase = lane << 6;
        unsigned long long mm = w0;
        while (mm) {
            int b = __ffsll((long long)mm) - 1;
            int p = pbase + b;
            float px = pts[3 * p], py = pts[3 * p + 1], pz = pts[3 * p + 2];
            float p2 = __fadd_rn(__fadd_rn(__fmul_rn(px, px), __fmul_rn(py, py)),
                                 __fmul_rn(pz, pz));
            float qp = __fadd_rn(__fadd_rn(__fmul_rn(qxx, px), __fmul_rn(qyy, py)),
                                 __fmul_rn(qzz, pz));
            float d2 = fmaxf(__fsub_rn(__fadd_rn(q2, p2), __fmul_rn(2.0f, qp)), 0.0f);
            out_idx[o] = (float)p;
            out_dist[o] = d2;
            ++o;
            mm &= mm - 1;
        }
        o = base + total0 + (i1 - c1);
        pbase = (lane + 64) << 6;
        mm = w1;
        while (mm) {
            int b = __ffsll((long long)mm) - 1;
            int p = pbase + b;
            float px = pts[3 * p], py = pts[3 * p + 1], pz = pts[3 * p + 2];
            float p2 = __fadd_rn(__fadd_rn(__fmul_rn(px, px), __fmul_rn(py, py)),
                                 __fmul_rn(pz, pz));
            float qp = __fadd_rn(__fadd_rn(__fmul_rn(qxx, px), __fmul_rn(qyy, py)),
                                 __fmul_rn(qzz, pz));
            float d2 = fmaxf(__fsub_rn(__fadd_rn(q2, p2), __fmul_rn(2.0f, qp)), 0.0f);
            out_idx[o] = (float)p;
            out_dist[o] = d2;
            ++o;
            mm &= mm - 1;
        }
    } else {
        // fallback: recompute + ballot pack (only if masks don't fit in ws)
        float r = rad[w];
        float r2 = __fmul_rn(r, r);
        int cum = 0;
        unsigned long long lanemask = (1ull << lane) - 1ull;
        for (int p0 = 0; p0 < N; p0 += 64) {
            int p = p0 + lane;
            float px = pts[3 * p], py = pts[3 * p + 1], pz = pts[3 * p + 2];
            float p2 = __fadd_rn(__fadd_rn(__fmul_rn(px, px), __fmul_rn(py, py)),
                                 __fmul_rn(pz, pz));
            float qp = __fadd_rn(__fadd_rn(__fmul_rn(qxx, px), __fmul_rn(qyy, py)),
                                 __fmul_rn(qzz, pz));
            float d2 = __fsub_rn(__fadd_rn(q2, p2), __fmul_rn(2.0f, qp));
            bool pred = (d2 <= r2);
            unsigned long long mask = __ballot(pred);
            if (pred) {
                long long pos = base + cum + __popcll(mask & lanemask);
                out_idx[pos] = (float)p;
                out_dist[pos] = fmaxf(d2, 0.0f);
            }
            cum += __popcll(mask);
        }
    }
}

extern "C" void kernel_launch(void* const* d_in, const int* in_sizes, int n_in,
                              void* d_out, int out_size, void* d_ws, size_t ws_size,
                              hipStream_t stream) {
    const float* points = (const float*)d_in[0];
    const float* queries = (const float*)d_in[1];
    const float* radii = (const float*)d_in[2];
    int N = in_sizes[0] / 3;
    int M = in_sizes[1] / 3;
    long long MN = (long long)M * (long long)N;

    float* out = (float*)d_out;
    float* out_idx = out;
    float* out_splits = out + MN;
    float* out_dist = out + MN + M + 1;

    // running-offset ws allocator (R2 lesson: never hand-sum offsets)
    char* ws = (char*)d_ws;
    size_t off = 0;
    auto take = [&](size_t bytes) -> size_t {
        size_t o = off;
        off += (bytes + 255) & ~(size_t)255;
        return o;
    };
    size_t o_counts = take((size_t)M * 4);
    size_t o_masks = take((size_t)M * (size_t)(N / 64) * 8);
    bool useMasks = (off <= ws_size) && (N <= 8192);  // write path assumes nw<=128

    int* counts = (int*)(ws + o_counts);
    unsigned long long* masks = (unsigned long long*)(ws + o_masks);

    int countBlocks = (M + 15) / 16;  // 4 waves x 4 queries per block
    int fillPerRegion = 768;
    int grid = countBlocks + 2 * fillPerRegion;
    rs_main<<<grid, 256, 0, stream>>>(points, queries, radii, counts, masks,
                                      useMasks ? 1 : 0, out, MN, N, M, countBlocks,
                                      fillPerRegion);
    int writeBlocks = (M + 15) / 16;  // 16 queries (waves) per 1024-thr block
    rs_write<<<writeBlocks, 1024, 0, stream>>>(points, queries, radii, counts, masks,
                                               useMasks ? 1 : 0, out_idx, out_splits,
                                               out_dist, N, M);
}